// Round 1
// baseline (224.005 us; speedup 1.0000x reference)
//
#include <hip/hip_runtime.h>
#include <hip/hip_bf16.h>
#include <cstdint>
#include <cmath>

#define BB 4
#define TT 2048
#define DD 512
#define RR 1024
#define MM (BB*RR)       // 4096
#define NBINS 13
#define LDXP (NBINS*DD)  // 6656

typedef __bf16 bf16;
typedef bf16 bf16x8 __attribute__((ext_vector_type(8)));
typedef bf16 bf16x2 __attribute__((ext_vector_type(2)));
typedef float f32x4 __attribute__((ext_vector_type(4)));

__device__ __forceinline__ float selu_f(float x) {
    const float sc = 1.0507009873554805f;
    const float aa = 1.6732632423543772f;
    return x > 0.0f ? sc * x : sc * aa * (expf(x) - 1.0f);
}

__device__ __forceinline__ void gload_lds16(const bf16* g, bf16* l) {
    __builtin_amdgcn_global_load_lds(
        (const __attribute__((address_space(1))) void*)g,
        (__attribute__((address_space(3))) void*)l, 16, 0, 0);
}

// Stage a [ROWS][32] bf16 tile (row-major, row stride lda in elements) into LDS.
// 256 threads; each issues 16B. LDS dest is linear; wave-uniform base + lane*16.
template<int ROWS>
__device__ __forceinline__ void stage_tile(const bf16* __restrict__ src, int lda,
                                           bf16* tile, int tid) {
#pragma unroll
    for (int it = 0; it < ROWS / 64; ++it) {
        int idx = it * 256 + tid;
        int row = idx >> 2;            // 4 lanes per 64B row
        int kk  = (idx & 3) * 8;       // element offset within row
        bf16* wavebase = tile + (idx >> 6) * 512;  // wave-uniform (1024B per wave)
        gload_lds16(src + (size_t)row * lda + kk, wavebase);
    }
}

// ---------------- weight prep ----------------
// Wdst[n][bin*512+d] = Wsrc[n][d*nbins+bin]
__global__ __launch_bounds__(256) void prep_w_interleave(const float* __restrict__ Wsrc,
                                                         bf16* __restrict__ Wdst,
                                                         int nbins, int Ktot) {
    int i = blockIdx.x * 256 + threadIdx.x;
    int total = 512 * Ktot;
    if (i >= total) return;
    int n = i / Ktot;
    int t = i - n * Ktot;
    int bin = t >> 9;
    int d = t & 511;
    Wdst[i] = (bf16)Wsrc[(size_t)n * Ktot + (size_t)d * nbins + bin];
}

__global__ __launch_bounds__(256) void prep_w_cast(const float* __restrict__ Wsrc,
                                                   bf16* __restrict__ Wdst, int total) {
    int i = blockIdx.x * 256 + threadIdx.x;
    if (i < total) Wdst[i] = (bf16)Wsrc[i];
}

// ---------------- pooling ----------------
// grid (4096, 13), block 256.  Xp[m][j*512+d] = lerp of feats rows.
__global__ __launch_bounds__(256) void pool_kernel(const float* __restrict__ feats,
                                                   const float* __restrict__ rois,
                                                   bf16* __restrict__ Xp) {
    int m = blockIdx.x;
    int j = blockIdx.y;
    int b = m >> 10;
    float s = rois[2 * m];
    float e = rois[2 * m + 1];
    float ext = 0.2f * (e - s);
    float pos;
    if (j < 2) {
        pos = (s - ext) + ((float)j + 0.5f) * ext;
    } else if (j < 11) {
        pos = s + (((float)(j - 2) + 0.5f) * (1.0f / 9.0f)) * (e - s);
    } else {
        pos = (e - ext) + ((float)(j - 11) + 0.5f) * ext;
    }
    pos = fminf(fmaxf(pos, 0.0f), (float)(TT - 1));
    float fl = floorf(pos);
    int lo = (int)fl;
    int hi = lo + 1; if (hi > TT - 1) hi = TT - 1;
    float w = pos - fl;
    const float* rlo = feats + ((size_t)b * TT + lo) * DD;
    const float* rhi = feats + ((size_t)b * TT + hi) * DD;
    int d0 = threadIdx.x * 2;
    float2 vlo = *(const float2*)(rlo + d0);
    float2 vhi = *(const float2*)(rhi + d0);
    float o0 = (1.0f - w) * vlo.x + w * vhi.x;
    float o1 = (1.0f - w) * vlo.y + w * vhi.y;
    bf16x2 o; o.x = (bf16)o0; o.y = (bf16)o1;
    *(bf16x2*)(Xp + (size_t)m * LDXP + j * DD + d0) = o;
}

// ---------------- GEMM kernels ----------------
// BM=64, BN=128, BK=32. 256 threads = 4 waves in 2x2; each wave 32x64 (2x4 frags).
// A: [M][lda] bf16 (row-major, K window contiguous). Bw: [512][K] bf16 (B^T layout).

// single-A GEMM with SELU epilogue; OUT_BF16 selects output type.
template<bool OUT_BF16>
__global__ __launch_bounds__(256) void gemm_selu_kernel(
    const bf16* __restrict__ A, int lda, int K,
    const bf16* __restrict__ Bw,
    const float* __restrict__ bias,
    void* __restrict__ Out, int ldo, int ocol0)
{
    __shared__ bf16 As[64 * 32];
    __shared__ bf16 Bs[128 * 32];
    int tid = threadIdx.x;
    int lane = tid & 63, w = tid >> 6;
    int wr = w >> 1, wc = w & 1;
    int m0 = blockIdx.x * 64;
    int n0 = blockIdx.y * 128;
    const bf16* Ab = A + (size_t)m0 * lda;
    const bf16* Bb = Bw + (size_t)n0 * K;
    int frow = lane & 15, fpack = (lane >> 4) * 8;
    f32x4 acc[2][4] = {};
    for (int k0 = 0; k0 < K; k0 += 32) {
        __syncthreads();
        stage_tile<64>(Ab + k0, lda, As, tid);
        stage_tile<128>(Bb + k0, K, Bs, tid);
        __syncthreads();
        bf16x8 af[2], bfr[4];
#pragma unroll
        for (int mf = 0; mf < 2; ++mf)
            af[mf] = *(const bf16x8*)(As + (wr * 32 + mf * 16 + frow) * 32 + fpack);
#pragma unroll
        for (int nf = 0; nf < 4; ++nf)
            bfr[nf] = *(const bf16x8*)(Bs + (wc * 64 + nf * 16 + frow) * 32 + fpack);
#pragma unroll
        for (int mf = 0; mf < 2; ++mf)
#pragma unroll
            for (int nf = 0; nf < 4; ++nf)
                acc[mf][nf] = __builtin_amdgcn_mfma_f32_16x16x32_bf16(af[mf], bfr[nf], acc[mf][nf], 0, 0, 0);
    }
    int crow = (lane >> 4) * 4;
    int ccol = lane & 15;
#pragma unroll
    for (int mf = 0; mf < 2; ++mf) {
#pragma unroll
        for (int nf = 0; nf < 4; ++nf) {
            int col = n0 + wc * 64 + nf * 16 + ccol;
            float bv = bias[col];
#pragma unroll
            for (int r2 = 0; r2 < 4; ++r2) {
                int row = m0 + wr * 32 + mf * 16 + crow + r2;
                float v = selu_f(acc[mf][nf][r2] + bv);
                if constexpr (OUT_BF16)
                    ((bf16*)Out)[(size_t)row * ldo + ocol0 + col] = (bf16)v;
                else
                    ((float*)Out)[(size_t)row * ldo + ocol0 + col] = v;
            }
        }
    }
}

// dual-A GEMM: C_L = Xleft@W^T, C_R = Xright@W^T sharing B tiles.
// epilogue writes selu(C_R+b) - selu(C_L+b) as bf16 into Y cols [0,512).
__global__ __launch_bounds__(256) void gemm_dual_kernel(
    const bf16* __restrict__ Xp,
    const bf16* __restrict__ Wl,   // [512][3584]
    const float* __restrict__ bias,
    bf16* __restrict__ Y)          // [M][1024]
{
    __shared__ bf16 AsL[64 * 32];
    __shared__ bf16 AsR[64 * 32];
    __shared__ bf16 Bs[128 * 32];
    int tid = threadIdx.x;
    int lane = tid & 63, w = tid >> 6;
    int wr = w >> 1, wc = w & 1;
    int m0 = blockIdx.x * 64;
    int n0 = blockIdx.y * 128;
    const int K = 3584;
    const bf16* AL = Xp + (size_t)m0 * LDXP;          // bins 0..6
    const bf16* AR = Xp + (size_t)m0 * LDXP + 3072;   // bins 6..12
    const bf16* Bb = Wl + (size_t)n0 * K;
    int frow = lane & 15, fpack = (lane >> 4) * 8;
    f32x4 accL[2][4] = {};
    f32x4 accR[2][4] = {};
    for (int k0 = 0; k0 < K; k0 += 32) {
        __syncthreads();
        stage_tile<64>(AL + k0, LDXP, AsL, tid);
        stage_tile<64>(AR + k0, LDXP, AsR, tid);
        stage_tile<128>(Bb + k0, K, Bs, tid);
        __syncthreads();
        bf16x8 afL[2], afR[2], bfr[4];
#pragma unroll
        for (int mf = 0; mf < 2; ++mf) {
            afL[mf] = *(const bf16x8*)(AsL + (wr * 32 + mf * 16 + frow) * 32 + fpack);
            afR[mf] = *(const bf16x8*)(AsR + (wr * 32 + mf * 16 + frow) * 32 + fpack);
        }
#pragma unroll
        for (int nf = 0; nf < 4; ++nf)
            bfr[nf] = *(const bf16x8*)(Bs + (wc * 64 + nf * 16 + frow) * 32 + fpack);
#pragma unroll
        for (int mf = 0; mf < 2; ++mf)
#pragma unroll
            for (int nf = 0; nf < 4; ++nf) {
                accL[mf][nf] = __builtin_amdgcn_mfma_f32_16x16x32_bf16(afL[mf], bfr[nf], accL[mf][nf], 0, 0, 0);
                accR[mf][nf] = __builtin_amdgcn_mfma_f32_16x16x32_bf16(afR[mf], bfr[nf], accR[mf][nf], 0, 0, 0);
            }
    }
    int crow = (lane >> 4) * 4;
    int ccol = lane & 15;
#pragma unroll
    for (int mf = 0; mf < 2; ++mf) {
#pragma unroll
        for (int nf = 0; nf < 4; ++nf) {
            int col = n0 + wc * 64 + nf * 16 + ccol;
            float bv = bias[col];
#pragma unroll
            for (int r2 = 0; r2 < 4; ++r2) {
                int row = m0 + wr * 32 + mf * 16 + crow + r2;
                float vL = selu_f(accL[mf][nf][r2] + bv);
                float vR = selu_f(accR[mf][nf][r2] + bv);
                Y[(size_t)row * 1024 + col] = (bf16)(vR - vL);
            }
        }
    }
}

// ---------------- launch ----------------
extern "C" void kernel_launch(void* const* d_in, const int* in_sizes, int n_in,
                              void* d_out, int out_size, void* d_ws, size_t ws_size,
                              hipStream_t stream) {
    const float* feats   = (const float*)d_in[0];
    const float* rois    = (const float*)d_in[3];
    const float* W_left  = (const float*)d_in[6];
    const float* b_left  = (const float*)d_in[7];
    const float* W_inner = (const float*)d_in[8];
    const float* b_inner = (const float*)d_in[9];
    const float* W_roi   = (const float*)d_in[10];
    const float* b_roi   = (const float*)d_in[11];
    float* out = (float*)d_out;

    // workspace layout (bf16 element offsets)
    bf16* wsb = (bf16*)d_ws;
    constexpr size_t XP_ELEMS = (size_t)MM * LDXP;          // 27,262,976
    constexpr size_t WL_ELEMS = (size_t)512 * 3584;
    constexpr size_t WI_ELEMS = (size_t)512 * 4608;
    constexpr size_t WR_ELEMS = (size_t)512 * 1024;
    bf16* Xp = wsb;
    bf16* Wl = Xp + XP_ELEMS;
    bf16* Wi = Wl + WL_ELEMS;
    bf16* Wr = Wi + WI_ELEMS;
    bf16* Y  = Wr + WR_ELEMS;                               // [M][1024]

    prep_w_interleave<<<(512 * 3584) / 256, 256, 0, stream>>>(W_left, Wl, 7, 3584);
    prep_w_interleave<<<(512 * 4608) / 256, 256, 0, stream>>>(W_inner, Wi, 9, 4608);
    prep_w_cast<<<(512 * 1024) / 256, 256, 0, stream>>>(W_roi, Wr, 512 * 1024);
    pool_kernel<<<dim3(MM, NBINS), 256, 0, stream>>>(feats, rois, Xp);

    dim3 gg(MM / 64, 512 / 128);
    // left+right fused (K=3584), writes Y[:,0:512)
    gemm_dual_kernel<<<gg, 256, 0, stream>>>(Xp, Wl, b_left, Y);
    // inner (K=4608, X window starts at bin 2), writes Y[:,512:1024)
    gemm_selu_kernel<true><<<gg, 256, 0, stream>>>(Xp + 1024, LDXP, 4608, Wi, b_inner, (void*)Y, 1024, 512);
    // final (K=1024), writes f32 output
    gemm_selu_kernel<false><<<gg, 256, 0, stream>>>(Y, 1024, 1024, Wr, b_roi, (void*)out, 512, 0);
}

// Round 2
// 146.319 us; speedup vs baseline: 1.5309x; 1.5309x over previous
//
#include <hip/hip_runtime.h>
#include <hip/hip_bf16.h>
#include <cstdint>
#include <cmath>

#define BB 4
#define TT 2048
#define DD 512
#define RR 1024
#define MM (BB*RR)       // 4096
#define NBINS 13
#define LDXP (NBINS*DD)  // 6656

typedef __bf16 bf16;
typedef bf16 bf16x8 __attribute__((ext_vector_type(8)));
typedef bf16 bf16x2 __attribute__((ext_vector_type(2)));
typedef float f32x4 __attribute__((ext_vector_type(4)));

__device__ __forceinline__ float selu_f(float x) {
    const float sc = 1.0507009873554805f;
    const float aa = 1.6732632423543772f;
    return x > 0.0f ? sc * x : sc * aa * (expf(x) - 1.0f);
}

__device__ __forceinline__ void gload_lds16(const bf16* g, bf16* l) {
    __builtin_amdgcn_global_load_lds(
        (const __attribute__((address_space(1))) void*)g,
        (__attribute__((address_space(3))) void*)l, 16, 0, 0);
}

__device__ __forceinline__ void waitb() {
    asm volatile("s_waitcnt vmcnt(0)" ::: "memory");
    __builtin_amdgcn_s_barrier();
}

// Stage a [ROWS][32] bf16 tile into LDS, XOR-swizzled: physical 16B slot p of
// row r holds global columns (p ^ ((r>>1)&3))*8 .. +7.  LDS dest stays linear
// (global_load_lds requirement); the source address carries the permutation.
template<int ROWS>
__device__ __forceinline__ void stage_tile(const bf16* __restrict__ src, int lda,
                                           bf16* tile, int tid) {
#pragma unroll
    for (int it = 0; it < ROWS / 64; ++it) {
        int idx = it * 256 + tid;
        int row = idx >> 2;                       // 4 slots of 16B per 64B row
        int col = ((idx & 3) ^ ((row >> 1) & 3)) * 8;
        bf16* wavebase = tile + (idx >> 6) * 512; // wave-uniform base (1024B/wave)
        gload_lds16(src + (size_t)row * lda + col, wavebase);
    }
}

// Fragment read with the matching XOR: logical slot s of row r lives at
// physical slot s ^ ((r>>1)&3).
__device__ __forceinline__ bf16x8 frd(const bf16* tile, int row, int s) {
    int p = s ^ ((row >> 1) & 3);
    return *(const bf16x8*)(tile + row * 32 + p * 8);
}

// ---------------- weight prep ----------------
__global__ __launch_bounds__(256) void prep_w_interleave(const float* __restrict__ Wsrc,
                                                         bf16* __restrict__ Wdst,
                                                         int nbins, int Ktot) {
    int i = blockIdx.x * 256 + threadIdx.x;
    int total = 512 * Ktot;
    if (i >= total) return;
    int n = i / Ktot;
    int t = i - n * Ktot;
    int bin = t >> 9;
    int d = t & 511;
    Wdst[i] = (bf16)Wsrc[(size_t)n * Ktot + (size_t)d * nbins + bin];
}

__global__ __launch_bounds__(256) void prep_w_cast(const float* __restrict__ Wsrc,
                                                   bf16* __restrict__ Wdst, int total) {
    int i = blockIdx.x * 256 + threadIdx.x;
    if (i < total) Wdst[i] = (bf16)Wsrc[i];
}

// ---------------- pooling ----------------
// one block per ROI; 256 threads cover D=512 as float2; loop over 13 bins.
__global__ __launch_bounds__(256) void pool_kernel(const float* __restrict__ feats,
                                                   const float* __restrict__ rois,
                                                   bf16* __restrict__ Xp) {
    int m = blockIdx.x;
    int b = m >> 10;
    float s = rois[2 * m];
    float e = rois[2 * m + 1];
    float ext = 0.2f * (e - s);
    int d0 = threadIdx.x * 2;
    bf16* orow = Xp + (size_t)m * LDXP + d0;
    const float* fb = feats + (size_t)b * TT * DD + d0;
#pragma unroll
    for (int j = 0; j < NBINS; ++j) {
        float pos;
        if (j < 2)       pos = (s - ext) + ((float)j + 0.5f) * ext;
        else if (j < 11) pos = s + (((float)(j - 2) + 0.5f) * (1.0f / 9.0f)) * (e - s);
        else             pos = (e - ext) + ((float)(j - 11) + 0.5f) * ext;
        pos = fminf(fmaxf(pos, 0.0f), (float)(TT - 1));
        float fl = floorf(pos);
        int lo = (int)fl;
        int hi = lo + 1; if (hi > TT - 1) hi = TT - 1;
        float w = pos - fl;
        float2 vlo = *(const float2*)(fb + (size_t)lo * DD);
        float2 vhi = *(const float2*)(fb + (size_t)hi * DD);
        bf16x2 o;
        o.x = (bf16)((1.0f - w) * vlo.x + w * vhi.x);
        o.y = (bf16)((1.0f - w) * vlo.y + w * vhi.y);
        *(bf16x2*)(orow + j * DD) = o;
    }
}

// ---------------- GEMM bodies ----------------
// BM=64, BN=128, BK=32; 256 threads = 4 waves (2x2), wave tile 32x64 (2x4 frags).
// Double-buffered LDS; prefetch issued before compute; one vmcnt(0)+s_barrier
// per K-step.

template<int K, bool OUT_BF16>
__device__ __forceinline__ void gemm_single_body(
    const bf16* __restrict__ A, int lda,
    const bf16* __restrict__ Bw, const float* __restrict__ bias,
    void* __restrict__ Out, int ldo, int ocol0,
    bf16* sm, int m0, int n0)
{
    int tid = threadIdx.x, lane = tid & 63, w = tid >> 6;
    int wr = w >> 1, wc = w & 1;
    const bf16* Ab = A + (size_t)m0 * lda;
    const bf16* Bb = Bw + (size_t)n0 * K;
    int frow = lane & 15, sl = lane >> 4;
    f32x4 acc[2][4] = {};
    bf16 *A0 = sm,        *B0 = sm + 2048;
    bf16 *A1 = sm + 8192, *B1 = sm + 8192 + 2048;

    auto stage = [&](bf16* as, bf16* bs, int t) {
        stage_tile<64>(Ab + t * 32, lda, as, tid);
        stage_tile<128>(Bb + t * 32, K, bs, tid);
    };
    auto compute = [&](const bf16* as, const bf16* bs) {
        bf16x8 af[2], bfr[4];
#pragma unroll
        for (int mf = 0; mf < 2; ++mf) af[mf] = frd(as, wr * 32 + mf * 16 + frow, sl);
#pragma unroll
        for (int nf = 0; nf < 4; ++nf) bfr[nf] = frd(bs, wc * 64 + nf * 16 + frow, sl);
#pragma unroll
        for (int mf = 0; mf < 2; ++mf)
#pragma unroll
            for (int nf = 0; nf < 4; ++nf)
                acc[mf][nf] = __builtin_amdgcn_mfma_f32_16x16x32_bf16(af[mf], bfr[nf], acc[mf][nf], 0, 0, 0);
    };

    constexpr int NT = K / 32;   // even for all instantiations
    stage(A0, B0, 0);
    waitb();
    for (int t = 0; t < NT; t += 2) {
        stage(A1, B1, t + 1);
        compute(A0, B0);
        waitb();
        if (t + 2 < NT) stage(A0, B0, t + 2);
        compute(A1, B1);
        waitb();
    }
    int crow = (lane >> 4) * 4;
    int ccol = lane & 15;
#pragma unroll
    for (int mf = 0; mf < 2; ++mf) {
#pragma unroll
        for (int nf = 0; nf < 4; ++nf) {
            int col = n0 + wc * 64 + nf * 16 + ccol;
            float bv = bias[col];
#pragma unroll
            for (int r2 = 0; r2 < 4; ++r2) {
                int row = m0 + wr * 32 + mf * 16 + crow + r2;
                float v = selu_f(acc[mf][nf][r2] + bv);
                if constexpr (OUT_BF16)
                    ((bf16*)Out)[(size_t)row * ldo + ocol0 + col] = (bf16)v;
                else
                    ((float*)Out)[(size_t)row * ldo + ocol0 + col] = v;
            }
        }
    }
}

template<int K>
__device__ __forceinline__ void gemm_dual_body(
    const bf16* __restrict__ Xp, const bf16* __restrict__ Wl,
    const float* __restrict__ bias, bf16* __restrict__ Y,
    bf16* sm, int m0, int n0)
{
    int tid = threadIdx.x, lane = tid & 63, w = tid >> 6;
    int wr = w >> 1, wc = w & 1;
    const bf16* AL = Xp + (size_t)m0 * LDXP;         // bins 0..6
    const bf16* AR = AL + 3072;                      // bins 6..12
    const bf16* Bb = Wl + (size_t)n0 * K;
    int frow = lane & 15, sl = lane >> 4;
    f32x4 accL[2][4] = {}, accR[2][4] = {};
    bf16 *L0 = sm,        *R0 = sm + 2048,        *B0 = sm + 4096;
    bf16 *L1 = sm + 8192, *R1 = sm + 8192 + 2048, *B1 = sm + 8192 + 4096;

    auto stage = [&](bf16* ls, bf16* rs, bf16* bs, int t) {
        stage_tile<64>(AL + t * 32, LDXP, ls, tid);
        stage_tile<64>(AR + t * 32, LDXP, rs, tid);
        stage_tile<128>(Bb + t * 32, K, bs, tid);
    };
    auto compute = [&](const bf16* ls, const bf16* rs, const bf16* bs) {
        bf16x8 afL[2], afR[2], bfr[4];
#pragma unroll
        for (int mf = 0; mf < 2; ++mf) {
            afL[mf] = frd(ls, wr * 32 + mf * 16 + frow, sl);
            afR[mf] = frd(rs, wr * 32 + mf * 16 + frow, sl);
        }
#pragma unroll
        for (int nf = 0; nf < 4; ++nf) bfr[nf] = frd(bs, wc * 64 + nf * 16 + frow, sl);
#pragma unroll
        for (int mf = 0; mf < 2; ++mf)
#pragma unroll
            for (int nf = 0; nf < 4; ++nf) {
                accL[mf][nf] = __builtin_amdgcn_mfma_f32_16x16x32_bf16(afL[mf], bfr[nf], accL[mf][nf], 0, 0, 0);
                accR[mf][nf] = __builtin_amdgcn_mfma_f32_16x16x32_bf16(afR[mf], bfr[nf], accR[mf][nf], 0, 0, 0);
            }
    };

    constexpr int NT = K / 32;   // 112
    stage(L0, R0, B0, 0);
    waitb();
    for (int t = 0; t < NT; t += 2) {
        stage(L1, R1, B1, t + 1);
        compute(L0, R0, B0);
        waitb();
        if (t + 2 < NT) stage(L0, R0, B0, t + 2);
        compute(L1, R1, B1);
        waitb();
    }
    int crow = (lane >> 4) * 4;
    int ccol = lane & 15;
#pragma unroll
    for (int mf = 0; mf < 2; ++mf) {
#pragma unroll
        for (int nf = 0; nf < 4; ++nf) {
            int col = n0 + wc * 64 + nf * 16 + ccol;
            float bv = bias[col];
#pragma unroll
            for (int r2 = 0; r2 < 4; ++r2) {
                int row = m0 + wr * 32 + mf * 16 + crow + r2;
                float vL = selu_f(accL[mf][nf][r2] + bv);
                float vR = selu_f(accR[mf][nf][r2] + bv);
                Y[(size_t)row * 1024 + col] = (bf16)(vR - vL);
            }
        }
    }
}

// ---------------- GEMM kernels ----------------
// wide: blocks 0..255 = dual (left/right, K=3584), 256..511 = inner (K=4608).
// 512 WGs on 256 CUs -> 2 blocks/CU; barriers of the co-resident blocks are
// uncorrelated so staging latency is hidden by the other block's MFMA.
__global__ __launch_bounds__(256) void wide_gemm(
    const bf16* __restrict__ Xp, const bf16* __restrict__ Wl,
    const float* __restrict__ bl, const bf16* __restrict__ Wi,
    const float* __restrict__ bi, bf16* __restrict__ Y)
{
    __shared__ bf16 sm[16384];  // 32 KB: 2 buffers x (64+64+128)x32
    int bid = blockIdx.x;
    if (bid < 256) {
        gemm_dual_body<3584>(Xp, Wl, bl, Y, sm, (bid & 63) * 64, (bid >> 6) * 128);
    } else {
        int b2 = bid - 256;
        gemm_single_body<4608, true>(Xp + 1024, LDXP, Wi, bi, (void*)Y, 1024, 512,
                                     sm, (b2 & 63) * 64, (b2 >> 6) * 128);
    }
}

__global__ __launch_bounds__(256) void final_gemm(
    const bf16* __restrict__ Y, const bf16* __restrict__ Wr,
    const float* __restrict__ br, float* __restrict__ out)
{
    __shared__ bf16 sm[16384];
    int bid = blockIdx.x;
    gemm_single_body<1024, false>(Y, 1024, Wr, br, (void*)out, 512, 0,
                                  sm, (bid & 63) * 64, (bid >> 6) * 128);
}

// ---------------- launch ----------------
extern "C" void kernel_launch(void* const* d_in, const int* in_sizes, int n_in,
                              void* d_out, int out_size, void* d_ws, size_t ws_size,
                              hipStream_t stream) {
    const float* feats   = (const float*)d_in[0];
    const float* rois    = (const float*)d_in[3];
    const float* W_left  = (const float*)d_in[6];
    const float* b_left  = (const float*)d_in[7];
    const float* W_inner = (const float*)d_in[8];
    const float* b_inner = (const float*)d_in[9];
    const float* W_roi   = (const float*)d_in[10];
    const float* b_roi   = (const float*)d_in[11];
    float* out = (float*)d_out;

    bf16* wsb = (bf16*)d_ws;
    constexpr size_t XP_ELEMS = (size_t)MM * LDXP;
    constexpr size_t WL_ELEMS = (size_t)512 * 3584;
    constexpr size_t WI_ELEMS = (size_t)512 * 4608;
    constexpr size_t WR_ELEMS = (size_t)512 * 1024;
    bf16* Xp = wsb;
    bf16* Wl = Xp + XP_ELEMS;
    bf16* Wi = Wl + WL_ELEMS;
    bf16* Wr = Wi + WI_ELEMS;
    bf16* Y  = Wr + WR_ELEMS;   // [M][1024]

    prep_w_interleave<<<(512 * 3584) / 256, 256, 0, stream>>>(W_left, Wl, 7, 3584);
    prep_w_interleave<<<(512 * 4608) / 256, 256, 0, stream>>>(W_inner, Wi, 9, 4608);
    prep_w_cast<<<(512 * 1024) / 256, 256, 0, stream>>>(W_roi, Wr, 512 * 1024);
    pool_kernel<<<MM, 256, 0, stream>>>(feats, rois, Xp);

    wide_gemm<<<512, 256, 0, stream>>>(Xp, Wl, b_left, Wi, b_inner, Y);
    final_gemm<<<256, 256, 0, stream>>>(Y, Wr, b_roi, out);
}

// Round 3
// 111.680 us; speedup vs baseline: 2.0058x; 1.3102x over previous
//
#include <hip/hip_runtime.h>
#include <hip/hip_bf16.h>
#include <cstdint>
#include <cmath>

#define BB 4
#define TT 2048
#define DD 512
#define RR 1024
#define MM (BB*RR)       // 4096
#define NBINS 13
#define LDXP (NBINS*DD)  // 6656

typedef __bf16 bf16;
typedef bf16 bf16x8 __attribute__((ext_vector_type(8)));
typedef bf16 bf16x2 __attribute__((ext_vector_type(2)));
typedef float f32x4 __attribute__((ext_vector_type(4)));

__device__ __forceinline__ float selu_f(float x) {
    const float sc = 1.0507009873554805f;
    const float aa = 1.6732632423543772f;
    return x > 0.0f ? sc * x : sc * aa * (expf(x) - 1.0f);
}

__device__ __forceinline__ void gload_lds16(const bf16* g, bf16* l) {
    __builtin_amdgcn_global_load_lds(
        (const __attribute__((address_space(1))) void*)g,
        (__attribute__((address_space(3))) void*)l, 16, 0, 0);
}

__device__ __forceinline__ void waitb() {
    asm volatile("s_waitcnt vmcnt(0)" ::: "memory");
    __builtin_amdgcn_s_barrier();
}

// Stage a [ROWS][64] bf16 tile into LDS, XOR-swizzled: physical 16B slot p of
// row r holds logical slot p ^ (r&7).  LDS dest stays linear (global_load_lds
// writes wave-base + lane*16); the source address carries the permutation.
template<int ROWS>
__device__ __forceinline__ void stage_tile64(const bf16* __restrict__ src, int lda,
                                             bf16* tile, int tid) {
#pragma unroll
    for (int it = 0; it < ROWS / 32; ++it) {     // 256 threads cover 32 rows/iter
        int idx = it * 256 + tid;
        int row = idx >> 3;                       // 8 slots of 16B per 128B row
        int col = ((idx & 7) ^ (row & 7)) * 8;
        bf16* wavebase = tile + (idx & ~63) * 8;  // wave-uniform base
        gload_lds16(src + (size_t)row * lda + col, wavebase);
    }
}

// Fragment read with the matching XOR: logical slot s of row r lives at
// physical slot s ^ (r&7).  16 lanes (rows r..r+15) spread over 8 slots -> 2-way.
__device__ __forceinline__ bf16x8 frd64(const bf16* tile, int row, int s) {
    int p = s ^ (row & 7);
    return *(const bf16x8*)(tile + row * 64 + p * 8);
}

// ---------------- fused prep: pool + weight transforms ----------------
template<int NB_, int KT>
__device__ __forceinline__ void w_interleave_body(const float* __restrict__ Wsrc,
                                                  bf16* __restrict__ Wdst, int i) {
    // Wdst[n][bin*512+d] = Wsrc[n][d*NB_+bin]
    int n = i / KT;                 // KT constexpr -> magic-mul
    int t = i - n * KT;
    int bin = t >> 9;
    int d = t & 511;
    Wdst[i] = (bf16)Wsrc[(size_t)n * KT + (size_t)d * NB_ + bin];
}

__device__ __forceinline__ void pool_body(const float* __restrict__ feats,
                                          const float* __restrict__ rois,
                                          bf16* __restrict__ Xp, int m, int tid) {
    int b = m >> 10;
    float s = rois[2 * m];
    float e = rois[2 * m + 1];
    float ext = 0.2f * (e - s);
    int d0 = tid * 2;
    bf16* orow = Xp + (size_t)m * LDXP + d0;
    const float* fb = feats + (size_t)b * TT * DD + d0;
#pragma unroll
    for (int j = 0; j < NBINS; ++j) {
        float pos;
        if (j < 2)       pos = (s - ext) + ((float)j + 0.5f) * ext;
        else if (j < 11) pos = s + (((float)(j - 2) + 0.5f) * (1.0f / 9.0f)) * (e - s);
        else             pos = (e - ext) + ((float)(j - 11) + 0.5f) * ext;
        pos = fminf(fmaxf(pos, 0.0f), (float)(TT - 1));
        float fl = floorf(pos);
        int lo = (int)fl;
        int hi = lo + 1; if (hi > TT - 1) hi = TT - 1;
        float w = pos - fl;
        float2 vlo = *(const float2*)(fb + (size_t)lo * DD);
        float2 vhi = *(const float2*)(fb + (size_t)hi * DD);
        bf16x2 o;
        o.x = (bf16)((1.0f - w) * vlo.x + w * vhi.x);
        o.y = (bf16)((1.0f - w) * vlo.y + w * vhi.y);
        *(bf16x2*)(orow + j * DD) = o;
    }
}

// blocks 0..4095: pool | 4096..11263: Wl | 11264..20479: Wi | 20480..22527: Wr
__global__ __launch_bounds__(256) void prep_all(
    const float* __restrict__ feats, const float* __restrict__ rois,
    const float* __restrict__ W_left, const float* __restrict__ W_inner,
    const float* __restrict__ W_roi,
    bf16* __restrict__ Xp, bf16* __restrict__ Wl, bf16* __restrict__ Wi,
    bf16* __restrict__ Wr)
{
    int bid = blockIdx.x, tid = threadIdx.x;
    if (bid < 4096) {
        pool_body(feats, rois, Xp, bid, tid);
    } else if (bid < 4096 + 7168) {
        int i = (bid - 4096) * 256 + tid;
        w_interleave_body<7, 3584>(W_left, Wl, i);
    } else if (bid < 4096 + 7168 + 9216) {
        int i = (bid - 11264) * 256 + tid;
        w_interleave_body<9, 4608>(W_inner, Wi, i);
    } else {
        int i = (bid - 20480) * 256 + tid;
        Wr[i] = (bf16)W_roi[i];
    }
}

// ---------------- GEMM bodies ----------------
// BM=64, BN=128, BK=64; 256 threads = 4 waves (2x2), wave tile 32x64 (2x4 frags).
// Double-buffered LDS; prefetch issued before compute; one vmcnt(0)+s_barrier
// per K-step (T3-minimal), s_setprio around the MFMA cluster (T5).

template<int K, bool OUT_BF16>
__device__ __forceinline__ void gemm_single_body(
    const bf16* __restrict__ A, int lda,
    const bf16* __restrict__ Bw, const float* __restrict__ bias,
    void* __restrict__ Out, int ldo, int ocol0,
    bf16* sm, int m0, int n0)
{
    int tid = threadIdx.x, lane = tid & 63, w = tid >> 6;
    int wr = w >> 1, wc = w & 1;
    const bf16* Ab = A + (size_t)m0 * lda;
    const bf16* Bb = Bw + (size_t)n0 * K;
    int frow = lane & 15, sl = lane >> 4;
    f32x4 acc[2][4] = {};
    bf16 *A0 = sm,         *B0 = sm + 4096;
    bf16 *A1 = sm + 12288, *B1 = sm + 12288 + 4096;

    auto stage = [&](bf16* as, bf16* bs, int t) {
        stage_tile64<64>(Ab + t * 64, lda, as, tid);
        stage_tile64<128>(Bb + t * 64, K, bs, tid);
    };
    auto compute = [&](const bf16* as, const bf16* bs) {
#pragma unroll
        for (int ks = 0; ks < 2; ++ks) {
            bf16x8 af[2], bfr[4];
#pragma unroll
            for (int mf = 0; mf < 2; ++mf) af[mf] = frd64(as, wr * 32 + mf * 16 + frow, ks * 4 + sl);
#pragma unroll
            for (int nf = 0; nf < 4; ++nf) bfr[nf] = frd64(bs, wc * 64 + nf * 16 + frow, ks * 4 + sl);
            __builtin_amdgcn_s_setprio(1);
#pragma unroll
            for (int mf = 0; mf < 2; ++mf)
#pragma unroll
                for (int nf = 0; nf < 4; ++nf)
                    acc[mf][nf] = __builtin_amdgcn_mfma_f32_16x16x32_bf16(af[mf], bfr[nf], acc[mf][nf], 0, 0, 0);
            __builtin_amdgcn_s_setprio(0);
        }
    };

    constexpr int NT = K / 64;   // even for all instantiations
    stage(A0, B0, 0);
    waitb();
    for (int t = 0; t < NT; t += 2) {
        stage(A1, B1, t + 1);
        compute(A0, B0);
        waitb();
        if (t + 2 < NT) stage(A0, B0, t + 2);
        compute(A1, B1);
        waitb();
    }
    int crow = (lane >> 4) * 4;
    int ccol = lane & 15;
#pragma unroll
    for (int mf = 0; mf < 2; ++mf) {
#pragma unroll
        for (int nf = 0; nf < 4; ++nf) {
            int col = n0 + wc * 64 + nf * 16 + ccol;
            float bv = bias[col];
#pragma unroll
            for (int r2 = 0; r2 < 4; ++r2) {
                int row = m0 + wr * 32 + mf * 16 + crow + r2;
                float v = selu_f(acc[mf][nf][r2] + bv);
                if constexpr (OUT_BF16)
                    ((bf16*)Out)[(size_t)row * ldo + ocol0 + col] = (bf16)v;
                else
                    ((float*)Out)[(size_t)row * ldo + ocol0 + col] = v;
            }
        }
    }
}

template<int K>
__device__ __forceinline__ void gemm_dual_body(
    const bf16* __restrict__ Xp, const bf16* __restrict__ Wl,
    const float* __restrict__ bias, bf16* __restrict__ Y,
    bf16* sm, int m0, int n0)
{
    int tid = threadIdx.x, lane = tid & 63, w = tid >> 6;
    int wr = w >> 1, wc = w & 1;
    const bf16* AL = Xp + (size_t)m0 * LDXP;         // bins 0..6
    const bf16* AR = AL + 3072;                      // bins 6..12
    const bf16* Bb = Wl + (size_t)n0 * K;
    int frow = lane & 15, sl = lane >> 4;
    f32x4 accL[2][4] = {}, accR[2][4] = {};
    bf16 *L0 = sm,         *R0 = sm + 4096,         *B0 = sm + 8192;
    bf16 *L1 = sm + 16384, *R1 = sm + 16384 + 4096, *B1 = sm + 16384 + 8192;

    auto stage = [&](bf16* ls, bf16* rs, bf16* bs, int t) {
        stage_tile64<64>(AL + t * 64, LDXP, ls, tid);
        stage_tile64<64>(AR + t * 64, LDXP, rs, tid);
        stage_tile64<128>(Bb + t * 64, K, bs, tid);
    };
    auto compute = [&](const bf16* ls, const bf16* rs, const bf16* bs) {
#pragma unroll
        for (int ks = 0; ks < 2; ++ks) {
            bf16x8 afL[2], afR[2], bfr[4];
#pragma unroll
            for (int mf = 0; mf < 2; ++mf) {
                afL[mf] = frd64(ls, wr * 32 + mf * 16 + frow, ks * 4 + sl);
                afR[mf] = frd64(rs, wr * 32 + mf * 16 + frow, ks * 4 + sl);
            }
#pragma unroll
            for (int nf = 0; nf < 4; ++nf) bfr[nf] = frd64(bs, wc * 64 + nf * 16 + frow, ks * 4 + sl);
            __builtin_amdgcn_s_setprio(1);
#pragma unroll
            for (int mf = 0; mf < 2; ++mf)
#pragma unroll
                for (int nf = 0; nf < 4; ++nf) {
                    accL[mf][nf] = __builtin_amdgcn_mfma_f32_16x16x32_bf16(afL[mf], bfr[nf], accL[mf][nf], 0, 0, 0);
                    accR[mf][nf] = __builtin_amdgcn_mfma_f32_16x16x32_bf16(afR[mf], bfr[nf], accR[mf][nf], 0, 0, 0);
                }
            __builtin_amdgcn_s_setprio(0);
        }
    };

    constexpr int NT = K / 64;   // 56
    stage(L0, R0, B0, 0);
    waitb();
    for (int t = 0; t < NT; t += 2) {
        stage(L1, R1, B1, t + 1);
        compute(L0, R0, B0);
        waitb();
        if (t + 2 < NT) stage(L0, R0, B0, t + 2);
        compute(L1, R1, B1);
        waitb();
    }
    int crow = (lane >> 4) * 4;
    int ccol = lane & 15;
#pragma unroll
    for (int mf = 0; mf < 2; ++mf) {
#pragma unroll
        for (int nf = 0; nf < 4; ++nf) {
            int col = n0 + wc * 64 + nf * 16 + ccol;
            float bv = bias[col];
#pragma unroll
            for (int r2 = 0; r2 < 4; ++r2) {
                int row = m0 + wr * 32 + mf * 16 + crow + r2;
                float vL = selu_f(accL[mf][nf][r2] + bv);
                float vR = selu_f(accR[mf][nf][r2] + bv);
                Y[(size_t)row * 1024 + col] = (bf16)(vR - vL);
            }
        }
    }
}

// ---------------- GEMM kernels ----------------
// blocks 0..255 = dual (K=3584), 256..511 = inner (K=4608); 2 blocks/CU.
__global__ __launch_bounds__(256) void wide_gemm(
    const bf16* __restrict__ Xp, const bf16* __restrict__ Wl,
    const float* __restrict__ bl, const bf16* __restrict__ Wi,
    const float* __restrict__ bi, bf16* __restrict__ Y)
{
    __shared__ bf16 sm[32768];  // 64 KB: 2 x (64+64+128)x64
    int bid = blockIdx.x;
    if (bid < 256) {
        gemm_dual_body<3584>(Xp, Wl, bl, Y, sm, (bid & 63) * 64, (bid >> 6) * 128);
    } else {
        int b2 = bid - 256;
        gemm_single_body<4608, true>(Xp + 1024, LDXP, Wi, bi, (void*)Y, 1024, 512,
                                     sm, (b2 & 63) * 64, (b2 >> 6) * 128);
    }
}

__global__ __launch_bounds__(256) void final_gemm(
    const bf16* __restrict__ Y, const bf16* __restrict__ Wr,
    const float* __restrict__ br, float* __restrict__ out)
{
    __shared__ bf16 sm[24576];  // 48 KB
    int bid = blockIdx.x;
    gemm_single_body<1024, false>(Y, 1024, Wr, br, (void*)out, 512, 0,
                                  sm, (bid & 63) * 64, (bid >> 6) * 128);
}

// ---------------- launch ----------------
extern "C" void kernel_launch(void* const* d_in, const int* in_sizes, int n_in,
                              void* d_out, int out_size, void* d_ws, size_t ws_size,
                              hipStream_t stream) {
    const float* feats   = (const float*)d_in[0];
    const float* rois    = (const float*)d_in[3];
    const float* W_left  = (const float*)d_in[6];
    const float* b_left  = (const float*)d_in[7];
    const float* W_inner = (const float*)d_in[8];
    const float* b_inner = (const float*)d_in[9];
    const float* W_roi   = (const float*)d_in[10];
    const float* b_roi   = (const float*)d_in[11];
    float* out = (float*)d_out;

    bf16* wsb = (bf16*)d_ws;
    constexpr size_t XP_ELEMS = (size_t)MM * LDXP;
    constexpr size_t WL_ELEMS = (size_t)512 * 3584;
    constexpr size_t WI_ELEMS = (size_t)512 * 4608;
    constexpr size_t WR_ELEMS = (size_t)512 * 1024;
    bf16* Xp = wsb;
    bf16* Wl = Xp + XP_ELEMS;
    bf16* Wi = Wl + WL_ELEMS;
    bf16* Wr = Wi + WI_ELEMS;
    bf16* Y  = Wr + WR_ELEMS;   // [M][1024]

    prep_all<<<22528, 256, 0, stream>>>(feats, rois, W_left, W_inner, W_roi,
                                        Xp, Wl, Wi, Wr);
    wide_gemm<<<512, 256, 0, stream>>>(Xp, Wl, b_left, Wi, b_inner, Y);
    final_gemm<<<256, 256, 0, stream>>>(Y, Wr, b_roi, out);
}

// Round 4
// 111.661 us; speedup vs baseline: 2.0061x; 1.0002x over previous
//
#include <hip/hip_runtime.h>
#include <hip/hip_bf16.h>
#include <cstdint>
#include <cmath>

#define BB 4
#define TT 2048
#define DD 512
#define RR 1024
#define MM (BB*RR)       // 4096
#define NBINS 13
#define LDXP (NBINS*DD)  // 6656

typedef __bf16 bf16;
typedef bf16 bf16x8 __attribute__((ext_vector_type(8)));
typedef bf16 bf16x2 __attribute__((ext_vector_type(2)));
typedef float f32x4 __attribute__((ext_vector_type(4)));

__device__ __forceinline__ float selu_f(float x) {
    const float sc = 1.0507009873554805f;
    const float aa = 1.6732632423543772f;
    return x > 0.0f ? sc * x : sc * aa * (expf(x) - 1.0f);
}

__device__ __forceinline__ void gload_lds16(const bf16* g, bf16* l) {
    __builtin_amdgcn_global_load_lds(
        (const __attribute__((address_space(1))) void*)g,
        (__attribute__((address_space(3))) void*)l, 16, 0, 0);
}

template<int N>
__device__ __forceinline__ void wait_vm() {
    if constexpr (N == 0)      asm volatile("s_waitcnt vmcnt(0)" ::: "memory");
    else if constexpr (N == 6) asm volatile("s_waitcnt vmcnt(6)" ::: "memory");
    else if constexpr (N == 8) asm volatile("s_waitcnt vmcnt(8)" ::: "memory");
}

// Stage a [ROWS][64] bf16 tile into LDS, XOR-swizzled: physical 16B slot p of
// row r holds logical slot p ^ (r&7).  LDS dest stays linear (global_load_lds
// writes wave-base + lane*16); the source address carries the permutation.
template<int ROWS>
__device__ __forceinline__ void stage_tile64(const bf16* __restrict__ src, int lda,
                                             bf16* tile, int tid) {
#pragma unroll
    for (int it = 0; it < ROWS / 32; ++it) {     // 256 threads cover 32 rows/iter
        int idx = it * 256 + tid;
        int row = idx >> 3;                       // 8 slots of 16B per 128B row
        int col = ((idx & 7) ^ (row & 7)) * 8;
        bf16* wavebase = tile + (idx & ~63) * 8;  // wave-uniform base
        gload_lds16(src + (size_t)row * lda + col, wavebase);
    }
}

// Fragment read with the matching XOR: logical slot s of row r lives at
// physical slot s ^ (r&7).  16 lanes (rows r..r+15) spread over 8 slots -> 2-way.
__device__ __forceinline__ bf16x8 frd64(const bf16* tile, int row, int s) {
    int p = s ^ (row & 7);
    return *(const bf16x8*)(tile + row * 64 + p * 8);
}

// ---------------- fused prep: pool + weight transforms ----------------
// Weight interleave as LDS-staged transpose: coalesced read AND write.
// Wdst[n][bin*512+d] = Wsrc[n][d*NB_+bin]
template<int NB_, int KT>
__device__ __forceinline__ void w_row_body(const float* __restrict__ Wsrc,
                                           bf16* __restrict__ Wdst,
                                           float* ld, int n, int tid) {
    const float* src = Wsrc + (size_t)n * KT;
    for (int i = tid; i < KT; i += 256) ld[i] = src[i];
    __syncthreads();
    bf16* dst = Wdst + (size_t)n * KT;
    for (int i = tid; i < KT; i += 256) {
        int bin = i >> 9, d = i & 511;
        dst[i] = (bf16)ld[d * NB_ + bin];
    }
}

__device__ __forceinline__ void pool_body(const float* __restrict__ feats,
                                          const float* __restrict__ rois,
                                          bf16* __restrict__ Xp, int m, int tid) {
    int b = m >> 10;
    float s = rois[2 * m];
    float e = rois[2 * m + 1];
    float ext = 0.2f * (e - s);
    int d0 = tid * 2;
    bf16* orow = Xp + (size_t)m * LDXP + d0;
    const float* fb = feats + (size_t)b * TT * DD + d0;
#pragma unroll
    for (int j = 0; j < NBINS; ++j) {
        float pos;
        if (j < 2)       pos = (s - ext) + ((float)j + 0.5f) * ext;
        else if (j < 11) pos = s + (((float)(j - 2) + 0.5f) * (1.0f / 9.0f)) * (e - s);
        else             pos = (e - ext) + ((float)(j - 11) + 0.5f) * ext;
        pos = fminf(fmaxf(pos, 0.0f), (float)(TT - 1));
        float fl = floorf(pos);
        int lo = (int)fl;
        int hi = lo + 1; if (hi > TT - 1) hi = TT - 1;
        float w = pos - fl;
        float2 vlo = *(const float2*)(fb + (size_t)lo * DD);
        float2 vhi = *(const float2*)(fb + (size_t)hi * DD);
        bf16x2 o;
        o.x = (bf16)((1.0f - w) * vlo.x + w * vhi.x);
        o.y = (bf16)((1.0f - w) * vlo.y + w * vhi.y);
        *(bf16x2*)(orow + j * DD) = o;
    }
}

// blocks 0..4095: pool | 4096..4607: Wl rows | 4608..5119: Wi rows | 5120..5631: Wr
__global__ __launch_bounds__(256) void prep_all(
    const float* __restrict__ feats, const float* __restrict__ rois,
    const float* __restrict__ W_left, const float* __restrict__ W_inner,
    const float* __restrict__ W_roi,
    bf16* __restrict__ Xp, bf16* __restrict__ Wl, bf16* __restrict__ Wi,
    bf16* __restrict__ Wr)
{
    __shared__ float ld[4608];
    int bid = blockIdx.x, tid = threadIdx.x;
    if (bid < 4096) {
        pool_body(feats, rois, Xp, bid, tid);
    } else if (bid < 4608) {
        w_row_body<7, 3584>(W_left, Wl, ld, bid - 4096, tid);
    } else if (bid < 5120) {
        w_row_body<9, 4608>(W_inner, Wi, ld, bid - 4608, tid);
    } else {
        int i0 = (bid - 5120) * 1024 + tid * 4;
        float4 v = *(const float4*)(W_roi + i0);
        bf16* d = Wr + i0;
        d[0] = (bf16)v.x; d[1] = (bf16)v.y; d[2] = (bf16)v.z; d[3] = (bf16)v.w;
    }
}

// ---------------- GEMM bodies ----------------
// BM=64, BN=128, BK=64; 256 threads = 4 waves (2x2), wave tile 32x64 (2x4 frags).
// 2-deep counted-vmcnt pipeline: tiles t and t+1 always in flight; vmcnt waits
// only for the older tile (never 0 in main loop); two barriers per K-step.

template<int K, bool OUT_BF16>
__device__ __forceinline__ void gemm_single_body(
    const bf16* __restrict__ A, int lda,
    const bf16* __restrict__ Bw, const float* __restrict__ bias,
    void* __restrict__ Out, int ldo, int ocol0,
    bf16* sm, int m0, int n0)
{
    int tid = threadIdx.x, lane = tid & 63, w = tid >> 6;
    int wr = w >> 1, wc = w & 1;
    const bf16* Ab = A + (size_t)m0 * lda;
    const bf16* Bb = Bw + (size_t)n0 * K;
    int frow = lane & 15, sl = lane >> 4;
    f32x4 acc[2][4] = {};
    bf16 *A0 = sm,         *B0 = sm + 4096;
    bf16 *A1 = sm + 12288, *B1 = sm + 12288 + 4096;

    auto stage = [&](bf16* as, bf16* bs, int t) {   // 6 loads/thread
        stage_tile64<64>(Ab + t * 64, lda, as, tid);
        stage_tile64<128>(Bb + t * 64, K, bs, tid);
    };
    auto compute = [&](const bf16* as, const bf16* bs) {
#pragma unroll
        for (int ks = 0; ks < 2; ++ks) {
            bf16x8 af[2], bfr[4];
#pragma unroll
            for (int mf = 0; mf < 2; ++mf) af[mf] = frd64(as, wr * 32 + mf * 16 + frow, ks * 4 + sl);
#pragma unroll
            for (int nf = 0; nf < 4; ++nf) bfr[nf] = frd64(bs, wc * 64 + nf * 16 + frow, ks * 4 + sl);
            __builtin_amdgcn_s_setprio(1);
#pragma unroll
            for (int mf = 0; mf < 2; ++mf)
#pragma unroll
                for (int nf = 0; nf < 4; ++nf)
                    acc[mf][nf] = __builtin_amdgcn_mfma_f32_16x16x32_bf16(af[mf], bfr[nf], acc[mf][nf], 0, 0, 0);
            __builtin_amdgcn_s_setprio(0);
        }
    };

    constexpr int NT = K / 64;   // >= 3 for all instantiations
    stage(A0, B0, 0);
    stage(A1, B1, 1);
    for (int t = 0; t + 2 < NT; ++t) {
        wait_vm<6>(); __builtin_amdgcn_s_barrier();
        const bf16 *as = (t & 1) ? A1 : A0, *bs = (t & 1) ? B1 : B0;
        compute(as, bs);
        __builtin_amdgcn_s_barrier();
        stage((t & 1) ? A1 : A0, (t & 1) ? B1 : B0, t + 2);
    }
    wait_vm<6>(); __builtin_amdgcn_s_barrier();
    { const bf16 *as = (NT & 1) ? A1 : A0, *bs = (NT & 1) ? B1 : B0; compute(as, bs); }
    wait_vm<0>(); __builtin_amdgcn_s_barrier();
    { const bf16 *as = (NT & 1) ? A0 : A1, *bs = (NT & 1) ? B0 : B1; compute(as, bs); }

    int crow = (lane >> 4) * 4;
    int ccol = lane & 15;
#pragma unroll
    for (int mf = 0; mf < 2; ++mf) {
#pragma unroll
        for (int nf = 0; nf < 4; ++nf) {
            int col = n0 + wc * 64 + nf * 16 + ccol;
            float bv = bias[col];
#pragma unroll
            for (int r2 = 0; r2 < 4; ++r2) {
                int row = m0 + wr * 32 + mf * 16 + crow + r2;
                float v = selu_f(acc[mf][nf][r2] + bv);
                if constexpr (OUT_BF16)
                    ((bf16*)Out)[(size_t)row * ldo + ocol0 + col] = (bf16)v;
                else
                    ((float*)Out)[(size_t)row * ldo + ocol0 + col] = v;
            }
        }
    }
}

template<int K>
__device__ __forceinline__ void gemm_dual_body(
    const bf16* __restrict__ Xp, const bf16* __restrict__ Wl,
    const float* __restrict__ bias, bf16* __restrict__ Y,
    bf16* sm, int m0, int n0)
{
    int tid = threadIdx.x, lane = tid & 63, w = tid >> 6;
    int wr = w >> 1, wc = w & 1;
    const bf16* AL = Xp + (size_t)m0 * LDXP;         // bins 0..6
    const bf16* AR = AL + 3072;                      // bins 6..12
    const bf16* Bb = Wl + (size_t)n0 * K;
    int frow = lane & 15, sl = lane >> 4;
    f32x4 accL[2][4] = {}, accR[2][4] = {};
    bf16 *L0 = sm,         *R0 = sm + 4096,         *B0 = sm + 8192;
    bf16 *L1 = sm + 16384, *R1 = sm + 16384 + 4096, *B1 = sm + 16384 + 8192;

    auto stage = [&](bf16* ls, bf16* rs, bf16* bs, int t) {  // 8 loads/thread
        stage_tile64<64>(AL + t * 64, LDXP, ls, tid);
        stage_tile64<64>(AR + t * 64, LDXP, rs, tid);
        stage_tile64<128>(Bb + t * 64, K, bs, tid);
    };
    auto compute = [&](const bf16* ls, const bf16* rs, const bf16* bs) {
#pragma unroll
        for (int ks = 0; ks < 2; ++ks) {
            bf16x8 afL[2], afR[2], bfr[4];
#pragma unroll
            for (int mf = 0; mf < 2; ++mf) {
                afL[mf] = frd64(ls, wr * 32 + mf * 16 + frow, ks * 4 + sl);
                afR[mf] = frd64(rs, wr * 32 + mf * 16 + frow, ks * 4 + sl);
            }
#pragma unroll
            for (int nf = 0; nf < 4; ++nf) bfr[nf] = frd64(bs, wc * 64 + nf * 16 + frow, ks * 4 + sl);
            __builtin_amdgcn_s_setprio(1);
#pragma unroll
            for (int mf = 0; mf < 2; ++mf)
#pragma unroll
                for (int nf = 0; nf < 4; ++nf) {
                    accL[mf][nf] = __builtin_amdgcn_mfma_f32_16x16x32_bf16(afL[mf], bfr[nf], accL[mf][nf], 0, 0, 0);
                    accR[mf][nf] = __builtin_amdgcn_mfma_f32_16x16x32_bf16(afR[mf], bfr[nf], accR[mf][nf], 0, 0, 0);
                }
            __builtin_amdgcn_s_setprio(0);
        }
    };

    constexpr int NT = K / 64;   // 56
    stage(L0, R0, B0, 0);
    stage(L1, R1, B1, 1);
    for (int t = 0; t + 2 < NT; ++t) {
        wait_vm<8>(); __builtin_amdgcn_s_barrier();
        const bf16 *ls = (t & 1) ? L1 : L0, *rs = (t & 1) ? R1 : R0, *bs = (t & 1) ? B1 : B0;
        compute(ls, rs, bs);
        __builtin_amdgcn_s_barrier();
        stage((t & 1) ? L1 : L0, (t & 1) ? R1 : R0, (t & 1) ? B1 : B0, t + 2);
    }
    wait_vm<8>(); __builtin_amdgcn_s_barrier();
    { const bf16 *ls = (NT & 1) ? L1 : L0, *rs = (NT & 1) ? R1 : R0, *bs = (NT & 1) ? B1 : B0;
      compute(ls, rs, bs); }
    wait_vm<0>(); __builtin_amdgcn_s_barrier();
    { const bf16 *ls = (NT & 1) ? L0 : L1, *rs = (NT & 1) ? R0 : R1, *bs = (NT & 1) ? B0 : B1;
      compute(ls, rs, bs); }

    int crow = (lane >> 4) * 4;
    int ccol = lane & 15;
#pragma unroll
    for (int mf = 0; mf < 2; ++mf) {
#pragma unroll
        for (int nf = 0; nf < 4; ++nf) {
            int col = n0 + wc * 64 + nf * 16 + ccol;
            float bv = bias[col];
#pragma unroll
            for (int r2 = 0; r2 < 4; ++r2) {
                int row = m0 + wr * 32 + mf * 16 + crow + r2;
                float vL = selu_f(accL[mf][nf][r2] + bv);
                float vR = selu_f(accR[mf][nf][r2] + bv);
                Y[(size_t)row * 1024 + col] = (bf16)(vR - vL);
            }
        }
    }
}

// ---------------- GEMM kernels ----------------
// blocks 0..255 = dual (K=3584), 256..511 = inner (K=4608); 2 blocks/CU.
__global__ __launch_bounds__(256) void wide_gemm(
    const bf16* __restrict__ Xp, const bf16* __restrict__ Wl,
    const float* __restrict__ bl, const bf16* __restrict__ Wi,
    const float* __restrict__ bi, bf16* __restrict__ Y)
{
    __shared__ bf16 sm[32768];  // 64 KB: 2 x (64+64+128)x64
    int bid = blockIdx.x;
    if (bid < 256) {
        gemm_dual_body<3584>(Xp, Wl, bl, Y, sm, (bid & 63) * 64, (bid >> 6) * 128);
    } else {
        int b2 = bid - 256;
        gemm_single_body<4608, true>(Xp + 1024, LDXP, Wi, bi, (void*)Y, 1024, 512,
                                     sm, (b2 & 63) * 64, (b2 >> 6) * 128);
    }
}

__global__ __launch_bounds__(256) void final_gemm(
    const bf16* __restrict__ Y, const bf16* __restrict__ Wr,
    const float* __restrict__ br, float* __restrict__ out)
{
    __shared__ bf16 sm[24576];  // 48 KB
    int bid = blockIdx.x;
    gemm_single_body<1024, false>(Y, 1024, Wr, br, (void*)out, 512, 0,
                                  sm, (bid & 63) * 64, (bid >> 6) * 128);
}

// ---------------- launch ----------------
extern "C" void kernel_launch(void* const* d_in, const int* in_sizes, int n_in,
                              void* d_out, int out_size, void* d_ws, size_t ws_size,
                              hipStream_t stream) {
    const float* feats   = (const float*)d_in[0];
    const float* rois    = (const float*)d_in[3];
    const float* W_left  = (const float*)d_in[6];
    const float* b_left  = (const float*)d_in[7];
    const float* W_inner = (const float*)d_in[8];
    const float* b_inner = (const float*)d_in[9];
    const float* W_roi   = (const float*)d_in[10];
    const float* b_roi   = (const float*)d_in[11];
    float* out = (float*)d_out;

    bf16* wsb = (bf16*)d_ws;
    constexpr size_t XP_ELEMS = (size_t)MM * LDXP;
    constexpr size_t WL_ELEMS = (size_t)512 * 3584;
    constexpr size_t WI_ELEMS = (size_t)512 * 4608;
    constexpr size_t WR_ELEMS = (size_t)512 * 1024;
    bf16* Xp = wsb;
    bf16* Wl = Xp + XP_ELEMS;
    bf16* Wi = Wl + WL_ELEMS;
    bf16* Wr = Wi + WI_ELEMS;
    bf16* Y  = Wr + WR_ELEMS;   // [M][1024]

    prep_all<<<5632, 256, 0, stream>>>(feats, rois, W_left, W_inner, W_roi,
                                       Xp, Wl, Wi, Wr);
    wide_gemm<<<512, 256, 0, stream>>>(Xp, Wl, b_left, Wi, b_inner, Y);
    final_gemm<<<256, 256, 0, stream>>>(Y, Wr, b_roi, out);
}